// Round 2
// baseline (338.859 us; speedup 1.0000x reference)
//
#include <hip/hip_runtime.h>

#define G_GROUPS 512
#define CNT      8192
#define S_PAIRS  8192
#define BLOCK    1024
#define WAVES    (BLOCK / 64)           // 16
#define REC_PER_WAVE (CNT / WAVES)      // 512 records per wave per tensor
#define SUB_REC  64                     // records per sub-iteration
#define SUB_ITERS (REC_PER_WAVE / SUB_REC)  // 8
#define SUB_F4   (SUB_REC * 9 / 4)      // 144 float4 per sub-chunk (2304 B)
#define PAIRS_PER_THREAD (S_PAIRS / BLOCK)  // 8

union U2H {
    unsigned int u;
    _Float16     h[2];
};

__global__ __launch_bounds__(BLOCK) void rgn_loss_kernel(
    const float4* __restrict__ inputs4,
    const float4* __restrict__ target4,
    const int*    __restrict__ left,
    const int*    __restrict__ right,
    float*        __restrict__ out)
{
    // Packed point table: 6 halves per point (in.xyz, tg.xyz) = 12 B -> 96 KiB
    __shared__ _Float16 ptsH[CNT * 6];
    // Per-wave private bounce for the 36B-record -> CA-row transpose: 16 x 2304 B = 36 KiB
    __shared__ float4 bounce4[WAVES * SUB_F4];
    __shared__ float red[WAVES];

    const int tid  = threadIdx.x;
    const int lane = tid & 63;
    const int wid  = tid >> 6;
    const int g    = blockIdx.x;
    const int gbase = g * CNT;

    // ---- Prefetch pair indices into registers (consumed after staging) ----
    const size_t pbase = (size_t)g * S_PAIRS;
    int li[PAIRS_PER_THREAD], ri[PAIRS_PER_THREAD];
    #pragma unroll
    for (int i = 0; i < PAIRS_PER_THREAD; ++i) {
        li[i] = left [pbase + tid + i * BLOCK] - gbase;   // group-local by construction
        ri[i] = right[pbase + tid + i * BLOCK] - gbase;
    }

    // ---- Staging: each wave streams its contiguous slice, no inter-wave sync ----
    float4* myb4 = &bounce4[wid * SUB_F4];
    const float* myb = (const float*)myb4;

    #pragma unroll
    for (int t = 0; t < 2; ++t) {
        const float4* src = (t == 0) ? inputs4 : target4;
        // wave's slice: records [wid*512, wid*512+512) of this group's tensor
        const size_t wbase_f4 = ((size_t)gbase + (size_t)wid * REC_PER_WAVE) * 9 / 4;
        for (int s = 0; s < SUB_ITERS; ++s) {
            const size_t cbase = wbase_f4 + (size_t)s * SUB_F4;
            // coalesced contiguous stream: 144 float4 per sub-chunk
            float4 v0 = src[cbase + lane];
            float4 v1 = src[cbase + lane + 64];
            float4 v2;
            if (lane < SUB_F4 - 128) v2 = src[cbase + lane + 128];
            myb4[lane]      = v0;
            myb4[lane + 64] = v1;
            if (lane < SUB_F4 - 128) myb4[lane + 128] = v2;
            // wave-synchronous LDS: in-order per-wave DS pipe makes RAW safe
            // extract CA row (floats 9r+3..9r+5) of record r = lane
            const float x = myb[9 * lane + 3];
            const float y = myb[9 * lane + 4];
            const float z = myb[9 * lane + 5];
            const int p = wid * REC_PER_WAVE + s * SUB_REC + lane;
            _Float16* dst = &ptsH[p * 6 + t * 3];
            dst[0] = (_Float16)x;     // stride-12B across lanes: 2-way bank alias = free
            dst[1] = (_Float16)y;
            dst[2] = (_Float16)z;
        }
    }
    __syncthreads();

    // ---- Gather pairs from the packed LDS table ----
    const unsigned int* ptsU = (const unsigned int*)ptsH;
    float acc = 0.0f;
    #pragma unroll
    for (int i = 0; i < PAIRS_PER_THREAD; ++i) {
        const int l3 = li[i] * 3;
        const int r3 = ri[i] * 3;
        U2H L0, L1, L2, R0, R1, R2;
        L0.u = ptsU[l3];     L1.u = ptsU[l3 + 1]; L2.u = ptsU[l3 + 2];
        R0.u = ptsU[r3];     R1.u = ptsU[r3 + 1]; R2.u = ptsU[r3 + 2];
        const float dix = (float)L0.h[0] - (float)R0.h[0];
        const float diy = (float)L0.h[1] - (float)R0.h[1];
        const float diz = (float)L1.h[0] - (float)R1.h[0];
        const float dtx = (float)L1.h[1] - (float)R1.h[1];
        const float dty = (float)L2.h[0] - (float)R2.h[0];
        const float dtz = (float)L2.h[1] - (float)R2.h[1];
        const float din = sqrtf(dix * dix + diy * diy + diz * diz);
        const float dtg = sqrtf(dtx * dtx + dty * dty + dtz * dtz);
        const float d   = din - dtg;
        acc += d * d;
    }

    // ---- Block reduction: wave shuffle -> LDS -> wave0 -> one atomic ----
    #pragma unroll
    for (int off = 32; off > 0; off >>= 1)
        acc += __shfl_down(acc, off);
    if (lane == 0) red[wid] = acc;
    __syncthreads();
    if (wid == 0) {
        float v = (lane < WAVES) ? red[lane] : 0.0f;
        #pragma unroll
        for (int off = 8; off > 0; off >>= 1)
            v += __shfl_down(v, off);
        if (lane == 0)
            atomicAdd(out, v * (1.0f / ((float)G_GROUPS * (float)S_PAIRS)));
    }
}

extern "C" void kernel_launch(void* const* d_in, const int* in_sizes, int n_in,
                              void* d_out, int out_size, void* d_ws, size_t ws_size,
                              hipStream_t stream) {
    const float4* inputs = (const float4*)d_in[0];
    const float4* target = (const float4*)d_in[1];
    const int*    left   = (const int*)d_in[2];
    const int*    right  = (const int*)d_in[3];
    float*        out    = (float*)d_out;

    hipMemsetAsync(out, 0, sizeof(float), stream);   // graph-capture safe
    rgn_loss_kernel<<<G_GROUPS, BLOCK, 0, stream>>>(inputs, target, left, right, out);
}

// Round 4
// 331.053 us; speedup vs baseline: 1.0236x; 1.0236x over previous
//
#include <hip/hip_runtime.h>

#define G_GROUPS 512
#define CNT      8192
#define S_PAIRS  8192
#define BLOCK    1024
#define WAVES    (BLOCK / 64)       // 16
#define RPW      (CNT / WAVES)      // 512 records per wave
#define CHUNKS   (RPW / 64)         // 8 async DMA instrs per wave per tensor
#define PPT      (S_PAIRS / BLOCK)  // 8 pairs per thread

typedef __attribute__((address_space(3))) void  lds_void;
typedef const __attribute__((address_space(1))) void g_void;

__global__ __launch_bounds__(BLOCK) void rgn_loss_kernel(
    const float* __restrict__ inputs,
    const float* __restrict__ target,
    const int*   __restrict__ left,
    const int*   __restrict__ right,
    float*       __restrict__ out)
{
    // CA-row table, ONE tensor at a time: 8192 pts x 16 B = 128 KiB.
    // Built by global_load_lds size=16 (measured-good width): lane i of a
    // 64-lane DMA loads record bytes [36r+12, 36r+28) -> tab4[r+i] = {x,y,z,junk}.
    __shared__ float4 tab4[CNT];
    __shared__ float  red[WAVES];

    const int tid   = threadIdx.x;
    const int lane  = tid & 63;
    const int wid   = tid >> 6;
    const int g     = blockIdx.x;
    const int gbase = g * CNT;

    // ---- Pair indices into registers (independent; overlaps staging DMA) ----
    const size_t pbase = (size_t)g * S_PAIRS;
    int li[PPT], ri[PPT];
    #pragma unroll
    for (int i = 0; i < PPT; ++i) {
        li[i] = left [pbase + tid + i * BLOCK] - gbase;   // group-local by construction
        ri[i] = right[pbase + tid + i * BLOCK] - gbase;
    }

    // ---- Phase 1: async-stage inputs CA rows. 8 DMAs/wave, ONE drain. ----
    {
        const int rbase = wid * RPW;
        #pragma unroll
        for (int c = 0; c < CHUNKS; ++c) {
            const int r = rbase + c * 64;                                   // wave-uniform
            const float* gp = inputs + (size_t)(gbase + r + lane) * 9 + 3;  // byte 36r+12
            __builtin_amdgcn_global_load_lds((g_void*)gp,
                                             (lds_void*)&tab4[r],
                                             16, 0, 0);
        }
    }
    __syncthreads();   // drain publishes the table

    // ---- Phase 2: gather d_in, park in VGPRs ----
    float din[PPT];
    #pragma unroll
    for (int i = 0; i < PPT; ++i) {
        const float4 L = tab4[li[i]];
        const float4 R = tab4[ri[i]];
        const float dx = L.x - R.x;
        const float dy = L.y - R.y;
        const float dz = L.z - R.z;
        din[i] = sqrtf(dx * dx + dy * dy + dz * dz);
    }
    __syncthreads();   // all reads complete before table overwrite

    // ---- Phase 3: async-stage target CA rows ----
    {
        const int rbase = wid * RPW;
        #pragma unroll
        for (int c = 0; c < CHUNKS; ++c) {
            const int r = rbase + c * 64;
            const float* gp = target + (size_t)(gbase + r + lane) * 9 + 3;
            __builtin_amdgcn_global_load_lds((g_void*)gp,
                                             (lds_void*)&tab4[r],
                                             16, 0, 0);
        }
    }
    __syncthreads();

    // ---- Phase 4: gather d_tg, accumulate squared difference ----
    float acc = 0.0f;
    #pragma unroll
    for (int i = 0; i < PPT; ++i) {
        const float4 L = tab4[li[i]];
        const float4 R = tab4[ri[i]];
        const float dx = L.x - R.x;
        const float dy = L.y - R.y;
        const float dz = L.z - R.z;
        const float d  = din[i] - sqrtf(dx * dx + dy * dy + dz * dz);
        acc += d * d;
    }

    // ---- Block reduction -> one atomic ----
    #pragma unroll
    for (int off = 32; off > 0; off >>= 1)
        acc += __shfl_down(acc, off);
    if (lane == 0) red[wid] = acc;
    __syncthreads();
    if (wid == 0) {
        float v = (lane < WAVES) ? red[lane] : 0.0f;
        #pragma unroll
        for (int off = 8; off > 0; off >>= 1)
            v += __shfl_down(v, off);
        if (lane == 0)
            atomicAdd(out, v * (1.0f / ((float)G_GROUPS * (float)S_PAIRS)));
    }
}

extern "C" void kernel_launch(void* const* d_in, const int* in_sizes, int n_in,
                              void* d_out, int out_size, void* d_ws, size_t ws_size,
                              hipStream_t stream) {
    const float* inputs = (const float*)d_in[0];
    const float* target = (const float*)d_in[1];
    const int*   left   = (const int*)d_in[2];
    const int*   right  = (const int*)d_in[3];
    float*       out    = (float*)d_out;

    hipMemsetAsync(out, 0, sizeof(float), stream);   // graph-capture safe
    rgn_loss_kernel<<<G_GROUPS, BLOCK, 0, stream>>>(inputs, target, left, right, out);
}